// Round 2
// baseline (111.174 us; speedup 1.0000x reference)
//
#include <hip/hip_runtime.h>
#include <hip/hip_bf16.h>

// BasicBlock (ReActNet-style) fused pipeline, MI355X gfx950.
// I/O dtype: FLOAT32 (per reference dtypes; round-1 NaN was f32-misread-as-bf16).
// conv3x3 & conv1x1 done as exact-integer bf16 MFMA GEMMs (activations/weights are signs).

typedef unsigned short u16;
typedef __bf16 bf16x8 __attribute__((ext_vector_type(8)));
typedef float  f32x4  __attribute__((ext_vector_type(4)));

#define GLD16(gsrc, ldst) \
  __builtin_amdgcn_global_load_lds((__attribute__((address_space(1))) void*)(gsrc), \
                                   (__attribute__((address_space(3))) void*)(ldst), 16, 0, 0)

__device__ __forceinline__ float b2f(u16 u) {
  union { unsigned int i; float f; } c; c.i = ((unsigned int)u) << 16; return c.f;
}
__device__ __forceinline__ u16 f2b(float f) {
  unsigned int u = __builtin_bit_cast(unsigned int, f);
  unsigned int r = (u + 0x7FFFu + ((u >> 16) & 1u)) >> 16;   // RNE
  return (u16)r;
}
__device__ __forceinline__ float sgnf(float v) {
  return (v > 0.f) ? 1.f : ((v < 0.f) ? -1.f : 0.f);
}

// ---------------- prep: binarize weights (transposed [o][k]), fold scale*BN, zero page, loss ----
__global__ __launch_bounds__(256) void prep_kernel(
    const float* __restrict__ w1, const float* __restrict__ w2,
    const float* __restrict__ g1, const float* __restrict__ be1,
    const float* __restrict__ m1, const float* __restrict__ v1,
    const float* __restrict__ g2, const float* __restrict__ be2,
    const float* __restrict__ m2, const float* __restrict__ v2,
    u16* __restrict__ wsgn1, u16* __restrict__ wsgn2,
    float* __restrict__ ab, float* __restrict__ zp,
    float* __restrict__ lossdst, const float* __restrict__ lossin)
{
  __shared__ float red[256];
  const int t = threadIdx.x;
  const int blk = blockIdx.x;
  float s = 0.f;
  if (blk < 256) {                       // w1: [o][i][3][3] -> wsgn1[o][(kh*3+kw)*256 + i]
    const int o = blk;
    for (int jj = t; jj < 2304; jj += 256) {
      float v = w1[o * 2304 + jj];
      s += fabsf(v);
      int i = jj / 9, sh = jj % 9;
      wsgn1[o * 2304 + sh * 256 + i] = f2b(sgnf(v));
    }
  } else {                               // w2: [o][i] -> wsgn2[o][i]
    const int o = blk - 256;
    float v = w2[o * 256 + t];
    s = fabsf(v);
    wsgn2[o * 256 + t] = f2b(sgnf(v));
  }
  red[t] = s;
  __syncthreads();
  for (int st = 128; st > 0; st >>= 1) { if (t < st) red[t] += red[t + st]; __syncthreads(); }
  if (t == 0) {
    if (blk < 256) {
      const int o = blk;
      float scale = red[0] / 2304.f;
      float inv = g1[o] / sqrtf(v1[o] + 1e-5f);
      ab[o]       = scale * inv;                 // alpha1
      ab[256 + o] = be1[o] - m1[o] * inv;        // beta1
    } else {
      const int o = blk - 256;
      float scale = red[0] / 256.f;
      float inv = g2[o] / sqrtf(v2[o] + 1e-5f);
      ab[512 + o] = scale * inv;                 // alpha2
      ab[768 + o] = be2[o] - m2[o] * inv;        // beta2
    }
  }
  if (blk == 0 && t < 64) zp[t] = 0.f;           // 256B zero page (conv padding gather)
  if (blk == 0 && t == 0) lossdst[0] = lossin[0];// loss passthrough (f32)
}

// ---------------- act1 = sign(x + b11), NCHW f32 -> NHWC bf16 transpose via LDS ----------------
__global__ __launch_bounds__(256) void act1_kernel(
    const float* __restrict__ x, const float* __restrict__ b11, u16* __restrict__ act1)
{
  __shared__ u16 lds[112 * 68];
  const int t = threadIdx.x;
  const int p0 = blockIdx.x * 112;     // 7 tiles * 112 = 784 pixels
  const int c0 = blockIdx.y * 64;      // 4 tiles * 64 = 256 ch
  const int b  = blockIdx.z;
  const float* xb = x + (size_t)b * 200704;
#pragma unroll
  for (int it = 0; it < 7; ++it) {     // read x coalesced (float4), sign, store LDS[p][c]
    int flat = it * 256 + t;           // (c:64, p4:28)
    int c = flat / 28;
    int p = (flat % 28) * 4;
    float4 v4 = *(const float4*)(xb + (size_t)(c0 + c) * 784 + p0 + p);
    float bb = b11[c0 + c];
    lds[(p + 0) * 68 + c] = f2b(sgnf(v4.x + bb));
    lds[(p + 1) * 68 + c] = f2b(sgnf(v4.y + bb));
    lds[(p + 2) * 68 + c] = f2b(sgnf(v4.z + bb));
    lds[(p + 3) * 68 + c] = f2b(sgnf(v4.w + bb));
  }
  __syncthreads();
#pragma unroll
  for (int it = 0; it < 7; ++it) {     // write act1 NHWC coalesced (ushort4)
    int flat = it * 256 + t;           // (p:112, c4:16)
    int p = flat / 16;
    int c = (flat % 16) * 4;
    ushort4 v4 = *(const ushort4*)(&lds[p * 68 + c]);
    *(ushort4*)(act1 + ((size_t)(b * 784 + p0 + p)) * 256 + c0 + c) = v4;
  }
}

// ---------------- GEMM (MODE 0: conv3x3 K=2304 ; MODE 1: conv1x1 K=256) ----------------
// Block tile 128px x 128ch, 4 waves (each 64x64), 16x16x32 bf16 MFMA.
// LDS: A[128][32], B[128][32] bf16, XOR chunk-swizzle ((row>>1)&3) => 2-way (free) banks.
// Staging via global_load_lds width16, pre-swizzled *global* source (m173 pattern).
template<int MODE>
__global__ __launch_bounds__(256, 2) void gemm_kernel(
    const u16* __restrict__ act,       // NHWC bf16 [25088][256]  (act1 or act2)
    const u16* __restrict__ wsgn,      // [256][KSTR] bf16 signs
    const float* __restrict__ alphav,  // [256]
    const float* __restrict__ betav,   // [256]
    const float* __restrict__ biasA,   // b12 / b22
    const float* __restrict__ slope,   // a1  / a2
    const float* __restrict__ biasB,   // b13 / b23
    const float* __restrict__ b21,     // MODE0 only
    const float* __restrict__ x,       // MODE0 only: NCHW f32 residual
    u16* __restrict__ out1b,           // MODE0: write bf16 ; MODE1: read (residual)
    u16* __restrict__ act2,            // MODE0: write sign(out1+b21) NHWC
    float* __restrict__ dout,          // MODE1: write NCHW f32
    const float* __restrict__ zp)      // zero page
{
  constexpr int KSTEPS = (MODE == 0) ? 72 : 8;
  constexpr int KSTR   = (MODE == 0) ? 2304 : 256;

  __shared__ u16 ldsA[128 * 32];
  __shared__ u16 ldsB[128 * 32];

  const int t = threadIdx.x;
  const int w = t >> 6;
  const int l = t & 63;
  const int blkPx = blockIdx.x * 128;
  const int blkCh = blockIdx.y * 128;

  // staging: chunk = q*4+w covers rows [chunk*16, chunk*16+16); lane l -> row chunk*16 + (l>>2)
  const int rc   = l >> 2;
  const int swzB = (((l & 3) ^ ((l >> 3) & 3)) << 4);  // pre-swizzled 16B chunk within 64B row
  int aPix[2], aH[2], aW[2], bRow[2];
#pragma unroll
  for (int q = 0; q < 2; ++q) {
    int row = (q * 4 + w) * 16 + rc;
    int p = blkPx + row;
    aPix[q] = p;
    int hw = p % 784;
    aH[q] = hw / 28;
    aW[q] = hw % 28;
    bRow[q] = blkCh + row;
  }

  // fragment read byte offsets (constant across K)
  const int pxBase = (w & 1) * 64;
  const int chBase = (w >> 1) * 64;
  int aoff[4], boff[4];
#pragma unroll
  for (int i = 0; i < 4; ++i) {
    int ra = pxBase + i * 16 + (l & 15);
    aoff[i] = ra * 64 + ((((l >> 4) ^ ((ra >> 1) & 3))) << 4);
    int rb = chBase + i * 16 + (l & 15);
    boff[i] = rb * 64 + ((((l >> 4) ^ ((rb >> 1) & 3))) << 4);
  }

  f32x4 acc[4][4];
  f32x4 zero4 = {0.f, 0.f, 0.f, 0.f};
#pragma unroll
  for (int i = 0; i < 4; ++i)
#pragma unroll
    for (int j = 0; j < 4; ++j) acc[i][j] = zero4;

  const char* actc = (const char*)act;
  const char* wsc  = (const char*)wsgn;
  const char* zpc  = (const char*)zp;
  char* ldsAc = (char*)ldsA;
  char* ldsBc = (char*)ldsB;

  for (int kk = 0; kk < KSTEPS; ++kk) {
    if (MODE == 0) {
      int shift = kk >> 3;
      int dh = shift / 3 - 1, dw = shift % 3 - 1;
      int kb = (kk & 7) * 64;
#pragma unroll
      for (int q = 0; q < 2; ++q) {
        bool ok = ((unsigned)(aH[q] + dh) < 28u) & ((unsigned)(aW[q] + dw) < 28u);
        const char* src = ok ? actc + (size_t)(aPix[q] + dh * 28 + dw) * 512 + kb + swzB
                             : zpc + swzB;
        GLD16(src, ldsAc + (q * 4 + w) * 1024 + l * 16);
      }
    } else {
#pragma unroll
      for (int q = 0; q < 2; ++q) {
        const char* src = actc + (size_t)aPix[q] * 512 + kk * 64 + swzB;
        GLD16(src, ldsAc + (q * 4 + w) * 1024 + l * 16);
      }
    }
#pragma unroll
    for (int q = 0; q < 2; ++q) {
      const char* src = wsc + (size_t)bRow[q] * (KSTR * 2) + kk * 64 + swzB;
      GLD16(src, ldsBc + (q * 4 + w) * 1024 + l * 16);
    }
    __syncthreads();   // drains vmcnt(0) -> LDS ready

    bf16x8 af[4], bfr[4];
#pragma unroll
    for (int i = 0; i < 4; ++i) {
      af[i]  = *(const bf16x8*)(ldsAc + aoff[i]);
      bfr[i] = *(const bf16x8*)(ldsBc + boff[i]);
    }
#pragma unroll
    for (int mi = 0; mi < 4; ++mi)
#pragma unroll
      for (int ni = 0; ni < 4; ++ni)
        acc[mi][ni] = __builtin_amdgcn_mfma_f32_16x16x32_bf16(af[mi], bfr[ni], acc[mi][ni], 0, 0, 0);
    __syncthreads();   // protect LDS before next stage
  }

  // ---------------- epilogue ----------------
  const int lane16 = l & 15;
  const int laneQ  = l >> 4;
  float al[4], bt[4], pA[4], pS[4], pB[4], p21[4];
#pragma unroll
  for (int ni = 0; ni < 4; ++ni) {
    int o = blkCh + chBase + ni * 16 + lane16;
    al[ni] = alphav[o];
    bt[ni] = betav[o];
    pA[ni] = biasA[o];
    pS[ni] = slope[o];
    pB[ni] = biasB[o];
    if (MODE == 0) p21[ni] = b21[o];
  }
#pragma unroll
  for (int mi = 0; mi < 4; ++mi) {
#pragma unroll
    for (int reg = 0; reg < 4; ++reg) {
      int p = blkPx + pxBase + mi * 16 + laneQ * 4 + reg;
      int bimg = p / 784;
      int hw = p % 784;
      size_t nchw = (size_t)bimg * 200704 + hw;
#pragma unroll
      for (int ni = 0; ni < 4; ++ni) {
        int o = blkCh + chBase + ni * 16 + lane16;
        float v = acc[mi][ni][reg] * al[ni] + bt[ni];
        if (MODE == 0) {
          v += x[nchw + (size_t)o * 784];             // residual x (f32)
          float t1 = v + pA[ni];
          t1 = (t1 > 0.f) ? t1 : pS[ni] * t1;         // PReLU
          float o1 = t1 + pB[ni];
          out1b[(size_t)p * 256 + o] = f2b(o1);
          act2[(size_t)p * 256 + o] = f2b(sgnf(o1 + p21[ni]));
        } else {
          v += b2f(out1b[(size_t)p * 256 + o]);       // residual out1 (bf16)
          float t1 = v + pA[ni];
          t1 = (t1 > 0.f) ? t1 : pS[ni] * t1;
          float o2 = t1 + pB[ni];
          dout[nchw + (size_t)o * 784] = o2;          // NCHW f32
        }
      }
    }
  }
}

// ---------------- launcher ----------------
extern "C" void kernel_launch(void* const* d_in, const int* in_sizes, int n_in,
                              void* d_out, int out_size, void* d_ws, size_t ws_size,
                              hipStream_t stream) {
  const float* x    = (const float*)d_in[0];
  const float* loss = (const float*)d_in[1];
  const float* b11  = (const float*)d_in[2];
  const float* b12  = (const float*)d_in[3];
  const float* b13  = (const float*)d_in[4];
  const float* b21  = (const float*)d_in[5];
  const float* b22  = (const float*)d_in[6];
  const float* b23  = (const float*)d_in[7];
  const float* w1   = (const float*)d_in[8];
  const float* w2   = (const float*)d_in[9];
  const float* g1   = (const float*)d_in[10];
  const float* be1  = (const float*)d_in[11];
  const float* m1   = (const float*)d_in[12];
  const float* v1   = (const float*)d_in[13];
  const float* g2   = (const float*)d_in[14];
  const float* be2  = (const float*)d_in[15];
  const float* m2   = (const float*)d_in[16];
  const float* v2   = (const float*)d_in[17];
  const float* a1   = (const float*)d_in[18];
  const float* a2   = (const float*)d_in[19];

  char* ws = (char*)d_ws;
  u16*   act1  = (u16*)(ws + 0ull);          // bf16 [25088][256] = 12,845,056 B
  u16*   act2  = (u16*)(ws + 12845056ull);   // bf16 [25088][256]
  u16*   out1b = (u16*)(ws + 25690112ull);   // bf16 [25088][256]
  u16*   wsgn1 = (u16*)(ws + 38535168ull);   // bf16 [256][2304]
  u16*   wsgn2 = (u16*)(ws + 39714816ull);   // bf16 [256][256]
  float* ab    = (float*)(ws + 39845888ull); // alpha1,beta1,alpha2,beta2 [4][256] f32
  float* zp    = (float*)(ws + 39849984ull); // 256 B zeros

  float* out = (float*)d_out;

  prep_kernel<<<512, 256, 0, stream>>>(w1, w2, g1, be1, m1, v1, g2, be2, m2, v2,
                                       wsgn1, wsgn2, ab, zp, out + (out_size - 1), loss);
  act1_kernel<<<dim3(7, 4, 32), 256, 0, stream>>>(x, b11, act1);
  gemm_kernel<0><<<dim3(196, 2), 256, 0, stream>>>(act1, wsgn1, ab, ab + 256,
      b12, a1, b13, b21, x, out1b, act2, (float*)nullptr, zp);
  gemm_kernel<1><<<dim3(196, 2), 256, 0, stream>>>(act2, wsgn2, ab + 512, ab + 768,
      b22, a2, b23, (const float*)nullptr, (const float*)nullptr, out1b, (u16*)nullptr, out, zp);
}

// Round 3
// 109.058 us; speedup vs baseline: 1.0194x; 1.0194x over previous
//
#include <hip/hip_runtime.h>
#include <hip/hip_bf16.h>

// BasicBlock (ReActNet-style) fused pipeline, MI355X gfx950.
// I/O dtype: FLOAT32. conv3x3 & conv1x1 as exact-integer bf16 MFMA GEMMs.
// R3: 64px x 128ch tiles (784 blocks, ~3/CU) + 2-phase double-buffered LDS
//     pipeline with raw s_barrier + explicit vmcnt (no full drain via __syncthreads).

typedef unsigned short u16;
typedef __bf16 bf16x8 __attribute__((ext_vector_type(8)));
typedef float  f32x4  __attribute__((ext_vector_type(4)));

#define GLD16(gsrc, ldst) \
  __builtin_amdgcn_global_load_lds((__attribute__((address_space(1))) void*)(gsrc), \
                                   (__attribute__((address_space(3))) void*)(ldst), 16, 0, 0)

__device__ __forceinline__ float b2f(u16 u) {
  union { unsigned int i; float f; } c; c.i = ((unsigned int)u) << 16; return c.f;
}
__device__ __forceinline__ u16 f2b(float f) {
  unsigned int u = __builtin_bit_cast(unsigned int, f);
  unsigned int r = (u + 0x7FFFu + ((u >> 16) & 1u)) >> 16;   // RNE
  return (u16)r;
}
__device__ __forceinline__ float sgnf(float v) {
  return (v > 0.f) ? 1.f : ((v < 0.f) ? -1.f : 0.f);
}

// ---------------- prep: binarize weights (transposed [o][k]), fold scale*BN, zero page, loss ----
__global__ __launch_bounds__(256) void prep_kernel(
    const float* __restrict__ w1, const float* __restrict__ w2,
    const float* __restrict__ g1, const float* __restrict__ be1,
    const float* __restrict__ m1, const float* __restrict__ v1,
    const float* __restrict__ g2, const float* __restrict__ be2,
    const float* __restrict__ m2, const float* __restrict__ v2,
    u16* __restrict__ wsgn1, u16* __restrict__ wsgn2,
    float* __restrict__ ab, float* __restrict__ zp,
    float* __restrict__ lossdst, const float* __restrict__ lossin)
{
  __shared__ float red[256];
  const int t = threadIdx.x;
  const int blk = blockIdx.x;
  float s = 0.f;
  if (blk < 256) {                       // w1: [o][i][3][3] -> wsgn1[o][(kh*3+kw)*256 + i]
    const int o = blk;
    for (int jj = t; jj < 2304; jj += 256) {
      float v = w1[o * 2304 + jj];
      s += fabsf(v);
      int i = jj / 9, sh = jj % 9;
      wsgn1[o * 2304 + sh * 256 + i] = f2b(sgnf(v));
    }
  } else {                               // w2: [o][i] -> wsgn2[o][i]
    const int o = blk - 256;
    float v = w2[o * 256 + t];
    s = fabsf(v);
    wsgn2[o * 256 + t] = f2b(sgnf(v));
  }
  red[t] = s;
  __syncthreads();
  for (int st = 128; st > 0; st >>= 1) { if (t < st) red[t] += red[t + st]; __syncthreads(); }
  if (t == 0) {
    if (blk < 256) {
      const int o = blk;
      float scale = red[0] / 2304.f;
      float inv = g1[o] / sqrtf(v1[o] + 1e-5f);
      ab[o]       = scale * inv;                 // alpha1
      ab[256 + o] = be1[o] - m1[o] * inv;        // beta1
    } else {
      const int o = blk - 256;
      float scale = red[0] / 256.f;
      float inv = g2[o] / sqrtf(v2[o] + 1e-5f);
      ab[512 + o] = scale * inv;                 // alpha2
      ab[768 + o] = be2[o] - m2[o] * inv;        // beta2
    }
  }
  if (blk == 0 && t < 64) zp[t] = 0.f;           // 256B zero page (conv padding gather)
  if (blk == 0 && t == 0) lossdst[0] = lossin[0];// loss passthrough (f32)
}

// ---------------- act1 = sign(x + b11), NCHW f32 -> NHWC bf16 transpose via LDS ----------------
__global__ __launch_bounds__(256) void act1_kernel(
    const float* __restrict__ x, const float* __restrict__ b11, u16* __restrict__ act1)
{
  __shared__ u16 lds[112 * 68];
  const int t = threadIdx.x;
  const int p0 = blockIdx.x * 112;     // 7 tiles * 112 = 784 pixels
  const int c0 = blockIdx.y * 64;      // 4 tiles * 64 = 256 ch
  const int b  = blockIdx.z;
  const float* xb = x + (size_t)b * 200704;
#pragma unroll
  for (int it = 0; it < 7; ++it) {     // read x coalesced (float4), sign, store LDS[p][c]
    int flat = it * 256 + t;           // (c:64, p4:28)
    int c = flat / 28;
    int p = (flat % 28) * 4;
    float4 v4 = *(const float4*)(xb + (size_t)(c0 + c) * 784 + p0 + p);
    float bb = b11[c0 + c];
    lds[(p + 0) * 68 + c] = f2b(sgnf(v4.x + bb));
    lds[(p + 1) * 68 + c] = f2b(sgnf(v4.y + bb));
    lds[(p + 2) * 68 + c] = f2b(sgnf(v4.z + bb));
    lds[(p + 3) * 68 + c] = f2b(sgnf(v4.w + bb));
  }
  __syncthreads();
#pragma unroll
  for (int it = 0; it < 7; ++it) {     // write act1 NHWC coalesced (ushort4)
    int flat = it * 256 + t;           // (p:112, c4:16)
    int p = flat / 16;
    int c = (flat % 16) * 4;
    ushort4 v4 = *(const ushort4*)(&lds[p * 68 + c]);
    *(ushort4*)(act1 + ((size_t)(b * 784 + p0 + p)) * 256 + c0 + c) = v4;
  }
}

// ---------------- GEMM (MODE 0: conv3x3 K=2304 ; MODE 1: conv1x1 K=256) ----------------
// Block tile 64px x 128ch, 4 waves (each 32x64), 16x16x32 bf16 MFMA, BK=32.
// 2-phase double-buffered: STAGE(next) issued before ds_read+MFMA(cur);
// raw s_barrier + explicit vmcnt(0) keeps the stage in flight under compute.
template<int MODE>
__global__ __launch_bounds__(256, 4) void gemm_kernel(
    const u16* __restrict__ act,       // NHWC bf16 [25088][256]
    const u16* __restrict__ wsgn,      // [256][KSTR] bf16 signs
    const float* __restrict__ alphav,
    const float* __restrict__ betav,
    const float* __restrict__ biasA,   // b12 / b22
    const float* __restrict__ slope,   // a1  / a2
    const float* __restrict__ biasB,   // b13 / b23
    const float* __restrict__ b21,     // MODE0 only
    const float* __restrict__ x,       // MODE0 only: NCHW f32 residual
    u16* __restrict__ out1b,           // MODE0: write bf16 ; MODE1: read (residual)
    u16* __restrict__ act2,            // MODE0: write sign(out1+b21) NHWC
    float* __restrict__ dout,          // MODE1: write NCHW f32
    const float* __restrict__ zp)
{
  constexpr int KSTEPS = (MODE == 0) ? 72 : 8;
  constexpr int KSTR   = (MODE == 0) ? 2304 : 256;

  __shared__ __align__(16) u16 ldsA[2][64 * 32];    // 2 x 4 KiB
  __shared__ __align__(16) u16 ldsB[2][128 * 32];   // 2 x 8 KiB

  const int t = threadIdx.x;
  const int w = t >> 6;
  const int l = t & 63;
  const int blkPx = blockIdx.x * 64;
  const int blkCh = blockIdx.y * 128;

  // staging geometry: wave w stages A rows [w*16,w*16+16), B chunks w and w+4
  const int rc   = l >> 2;
  const int swzB = (((l & 3) ^ ((rc >> 1) & 3)) << 4);  // XOR chunk swizzle (2-way banks = free)
  const int aPix = blkPx + w * 16 + rc;
  const int hw0  = aPix % 784;
  const int aH   = hw0 / 28, aW = hw0 % 28;
  const int bRow0 = blkCh + w * 16 + rc;
  const int bRow1 = blkCh + 64 + w * 16 + rc;

  // fragment read byte offsets (constant across K)
  const int pxBase = (w & 1) * 32;
  const int chBase = (w >> 1) * 64;
  int aoff[2], boff[4];
#pragma unroll
  for (int i = 0; i < 2; ++i) {
    int ra = pxBase + i * 16 + (l & 15);
    aoff[i] = ra * 64 + (((l >> 4) ^ ((ra >> 1) & 3)) << 4);
  }
#pragma unroll
  for (int i = 0; i < 4; ++i) {
    int rb = chBase + i * 16 + (l & 15);
    boff[i] = rb * 64 + (((l >> 4) ^ ((rb >> 1) & 3)) << 4);
  }

  f32x4 acc[2][4];
  f32x4 zero4 = {0.f, 0.f, 0.f, 0.f};
#pragma unroll
  for (int i = 0; i < 2; ++i)
#pragma unroll
    for (int j = 0; j < 4; ++j) acc[i][j] = zero4;

  const char* actc = (const char*)act;
  const char* wsc  = (const char*)wsgn;
  const char* zpc  = (const char*)zp;
  char* A0 = (char*)&ldsA[0][0];
  char* B0 = (char*)&ldsB[0][0];

  auto STAGE = [&](int buf, int kk) {
    char* dA = A0 + buf * 4096;
    char* dB = B0 + buf * 8192;
    if (MODE == 0) {
      int shift = kk >> 3;
      int dh = shift / 3 - 1, dw = shift % 3 - 1;
      int kb = (kk & 7) * 64;
      bool ok = ((unsigned)(aH + dh) < 28u) & ((unsigned)(aW + dw) < 28u);
      const char* srcA = ok ? actc + (size_t)(aPix + dh * 28 + dw) * 512 + kb + swzB
                            : zpc + swzB;
      GLD16(srcA, dA + w * 1024 + l * 16);
    } else {
      GLD16(actc + (size_t)aPix * 512 + kk * 64 + swzB, dA + w * 1024 + l * 16);
    }
    GLD16(wsc + (size_t)bRow0 * (KSTR * 2) + kk * 64 + swzB, dB + w * 1024 + l * 16);
    GLD16(wsc + (size_t)bRow1 * (KSTR * 2) + kk * 64 + swzB, dB + (w + 4) * 1024 + l * 16);
  };

  auto COMPUTE = [&](int buf) {
    const char* sA = A0 + buf * 4096;
    const char* sB = B0 + buf * 8192;
    bf16x8 af[2], bfr[4];
#pragma unroll
    for (int i = 0; i < 2; ++i) af[i]  = *(const bf16x8*)(sA + aoff[i]);
#pragma unroll
    for (int i = 0; i < 4; ++i) bfr[i] = *(const bf16x8*)(sB + boff[i]);
#pragma unroll
    for (int mi = 0; mi < 2; ++mi)
#pragma unroll
      for (int ni = 0; ni < 4; ++ni)
        acc[mi][ni] = __builtin_amdgcn_mfma_f32_16x16x32_bf16(af[mi], bfr[ni], acc[mi][ni], 0, 0, 0);
  };

  // prologue
  STAGE(0, 0);
  asm volatile("s_waitcnt vmcnt(0)" ::: "memory");
  __builtin_amdgcn_s_barrier();

#pragma unroll 1
  for (int kk = 0; kk < KSTEPS; kk += 2) {
    // phase 0: stage kk+1 into buf1, compute kk from buf0
    if (kk + 1 < KSTEPS) STAGE(1, kk + 1);
    COMPUTE(0);
    asm volatile("s_waitcnt vmcnt(0)" ::: "memory");
    __builtin_amdgcn_s_barrier();
    // phase 1: stage kk+2 into buf0, compute kk+1 from buf1
    if (kk + 2 < KSTEPS) STAGE(0, kk + 2);
    COMPUTE(1);
    asm volatile("s_waitcnt vmcnt(0)" ::: "memory");
    __builtin_amdgcn_s_barrier();
  }

  // ---------------- epilogue ----------------
  const int lane16 = l & 15;
  const int laneQ  = l >> 4;
  float al[4], bt[4], pA[4], pS[4], pB[4], p21[4];
#pragma unroll
  for (int ni = 0; ni < 4; ++ni) {
    int o = blkCh + chBase + ni * 16 + lane16;
    al[ni] = alphav[o];
    bt[ni] = betav[o];
    pA[ni] = biasA[o];
    pS[ni] = slope[o];
    pB[ni] = biasB[o];
    if (MODE == 0) p21[ni] = b21[o];
  }
#pragma unroll
  for (int mi = 0; mi < 2; ++mi) {
#pragma unroll
    for (int reg = 0; reg < 4; ++reg) {
      int p = blkPx + pxBase + mi * 16 + laneQ * 4 + reg;
      int bimg = p / 784;
      int hw = p % 784;
      size_t nchw = (size_t)bimg * 200704 + hw;
#pragma unroll
      for (int ni = 0; ni < 4; ++ni) {
        int o = blkCh + chBase + ni * 16 + lane16;
        float v = acc[mi][ni][reg] * al[ni] + bt[ni];
        if (MODE == 0) {
          v += x[nchw + (size_t)o * 784];             // residual x (f32)
          float t1 = v + pA[ni];
          t1 = (t1 > 0.f) ? t1 : pS[ni] * t1;         // PReLU
          float o1 = t1 + pB[ni];
          out1b[(size_t)p * 256 + o] = f2b(o1);
          act2[(size_t)p * 256 + o] = f2b(sgnf(o1 + p21[ni]));
        } else {
          v += b2f(out1b[(size_t)p * 256 + o]);       // residual out1 (bf16)
          float t1 = v + pA[ni];
          t1 = (t1 > 0.f) ? t1 : pS[ni] * t1;
          float o2 = t1 + pB[ni];
          dout[nchw + (size_t)o * 784] = o2;          // NCHW f32
        }
      }
    }
  }
}

// ---------------- launcher ----------------
extern "C" void kernel_launch(void* const* d_in, const int* in_sizes, int n_in,
                              void* d_out, int out_size, void* d_ws, size_t ws_size,
                              hipStream_t stream) {
  const float* x    = (const float*)d_in[0];
  const float* loss = (const float*)d_in[1];
  const float* b11  = (const float*)d_in[2];
  const float* b12  = (const float*)d_in[3];
  const float* b13  = (const float*)d_in[4];
  const float* b21  = (const float*)d_in[5];
  const float* b22  = (const float*)d_in[6];
  const float* b23  = (const float*)d_in[7];
  const float* w1   = (const float*)d_in[8];
  const float* w2   = (const float*)d_in[9];
  const float* g1   = (const float*)d_in[10];
  const float* be1  = (const float*)d_in[11];
  const float* m1   = (const float*)d_in[12];
  const float* v1   = (const float*)d_in[13];
  const float* g2   = (const float*)d_in[14];
  const float* be2  = (const float*)d_in[15];
  const float* m2   = (const float*)d_in[16];
  const float* v2   = (const float*)d_in[17];
  const float* a1   = (const float*)d_in[18];
  const float* a2   = (const float*)d_in[19];

  char* ws = (char*)d_ws;
  u16*   act1  = (u16*)(ws + 0ull);          // bf16 [25088][256] = 12,845,056 B
  u16*   act2  = (u16*)(ws + 12845056ull);   // bf16 [25088][256]
  u16*   out1b = (u16*)(ws + 25690112ull);   // bf16 [25088][256]
  u16*   wsgn1 = (u16*)(ws + 38535168ull);   // bf16 [256][2304]
  u16*   wsgn2 = (u16*)(ws + 39714816ull);   // bf16 [256][256]
  float* ab    = (float*)(ws + 39845888ull); // alpha1,beta1,alpha2,beta2 [4][256] f32
  float* zp    = (float*)(ws + 39849984ull); // 256 B zeros

  float* out = (float*)d_out;

  prep_kernel<<<512, 256, 0, stream>>>(w1, w2, g1, be1, m1, v1, g2, be2, m2, v2,
                                       wsgn1, wsgn2, ab, zp, out + (out_size - 1), loss);
  act1_kernel<<<dim3(7, 4, 32), 256, 0, stream>>>(x, b11, act1);
  gemm_kernel<0><<<dim3(392, 2), 256, 0, stream>>>(act1, wsgn1, ab, ab + 256,
      b12, a1, b13, b21, x, out1b, act2, (float*)nullptr, zp);
  gemm_kernel<1><<<dim3(392, 2), 256, 0, stream>>>(act2, wsgn2, ab + 512, ab + 768,
      b22, a2, b23, (const float*)nullptr, (const float*)nullptr, out1b, (u16*)nullptr, out, zp);
}